// Round 1
// baseline (484.353 us; speedup 1.0000x reference)
//
#include <hip/hip_runtime.h>
#include <hip/hip_bf16.h>

// ===========================================================================
// WindowedAttention: B=8, N=4096, C=768, H=12, HD=64, W=16 -> 16 windows x 256
// I/O float32; internal bf16 MFMA, fp32 accumulate.
//   k0 conv_x/conv_w: f32 -> bf16 pre-pass; x is written WINDOW-PERMUTED so
//                     qkv_gemm A-rows are linear (enables global_load_lds).
//   k1 qkv_gemm_bf  : m97-style (global_load_lds w=16, unpadded 64B LDS rows)
//   k2 attn_mfma    : flash-style per (b,w,h), unchanged from round 3.
//                     Writes attn_buf into the dead xb plane (orig token order)
//   k3 proj_gemm_bf : m97-style, epilogue f32 + bias -> d_out
// ws planes (bf16): [0]=xb->attn_buf, [1]=q, [2]=k, [3]=v, then wb_qkv, wb_proj
// total (4*25165824 + 2304*768 + 768*768)*2 = 206 MB. Fallback to round-3
// convert-in-staging kernels if ws_size is smaller.
//
// R0 change: bijective XCD-aware block swizzle in GEMM_CORE (T1). Grids are
// 4608 and 1536 blocks (both %8==0) so (id&7)*cpx+(id>>3) is bijective.
// ===========================================================================

using short8  = __attribute__((ext_vector_type(8))) short;
using short4v = __attribute__((ext_vector_type(4))) short;
using floatx4 = __attribute__((ext_vector_type(4))) float;

#define B_    8
#define N_    4096
#define C_    768
#define H_    12
#define HD_   64
#define NW_   256
#define SCALE_ 0.125f
#define QKV_PLANE ((size_t)25165824)   // B*16*12*256*64 == B*N*C

__device__ __forceinline__ float bf2f(unsigned short u) {
  union { unsigned int i; float f; } c; c.i = ((unsigned int)u) << 16; return c.f;
}
__device__ __forceinline__ unsigned short f2bf(float f) {
  unsigned int u = __float_as_uint(f);
  u += 0x7fffu + ((u >> 16) & 1u);   // RNE
  return (unsigned short)(u >> 16);
}
__device__ __forceinline__ short4v f4bf(floatx4 f) {
  short4v s;
  s[0] = (short)f2bf(f[0]); s[1] = (short)f2bf(f[1]);
  s[2] = (short)f2bf(f[2]); s[3] = (short)f2bf(f[3]);
  return s;
}
__device__ __forceinline__ int perm_n(int w, int t) {
  int rb = w >> 2, cb = w & 3, ri = t >> 4, ci = t & 15;
  return ((rb << 4) + ri) * 64 + (cb << 4) + ci;
}
__device__ __forceinline__ void glds16(const unsigned short* g, short* l) {
  __builtin_amdgcn_global_load_lds(
      (const __attribute__((address_space(1))) unsigned int*)g,
      (__attribute__((address_space(3))) unsigned int*)l, 16, 0, 0);
}

// ---------------------------------------------------------------------------
// conv_x: x f32 [b][n][c] -> xb bf16 [b][p][c] with p in window-permuted order
// ---------------------------------------------------------------------------
__global__ __launch_bounds__(192) void conv_x(
    const float* __restrict__ x, unsigned short* __restrict__ xb) {
  int row = blockIdx.x;               // b*4096 + p
  int b = row >> 12, p = row & 4095;
  int n = perm_n(p >> 8, p & 255);
  const float* src = x + ((size_t)(b << 12) + (size_t)n) * C_;
  unsigned short* dst = xb + (size_t)row * C_;
  int c = threadIdx.x << 2;
  *(short4v*)(dst + c) = f4bf(*(const floatx4*)(src + c));
}

// conv_w: qkv_w (2304x768) and proj_w (768x768) f32 -> bf16
__global__ __launch_bounds__(192) void conv_w(
    const float* __restrict__ qw, const float* __restrict__ pw,
    unsigned short* __restrict__ wq, unsigned short* __restrict__ wp) {
  int row = blockIdx.x;
  const float* src; unsigned short* dst;
  if (row < 2304) { src = qw + (size_t)row * C_; dst = wq + (size_t)row * C_; }
  else { src = pw + (size_t)(row - 2304) * C_; dst = wp + (size_t)(row - 2304) * C_; }
  int c = threadIdx.x << 2;
  *(short4v*)(dst + c) = f4bf(*(const floatx4*)(src + c));
}

// ---------------------------------------------------------------------------
// m97-style bf16 GEMM core: 128x128 tile, BK=32, unpadded 64B LDS rows,
// global_load_lds width-16 staging (lane-linear LDS dest). 256 thr = 4 waves.
// XCD-aware bijective block swizzle: gridDim.x==256 in all uses; grid size
// divisible by 8, so (id&7)*cpx+(id>>3) is a bijection and bm/bn stay in range.
// ---------------------------------------------------------------------------
#define GEMM_CORE(Aptr, Bptr)                                                  \
  __shared__ short As[128 * 32];                                               \
  __shared__ short Bs[128 * 32];                                               \
  const int tid  = threadIdx.x;                                                \
  const int id0  = (int)(blockIdx.y * gridDim.x + blockIdx.x);                 \
  const int cpx  = (int)(gridDim.x * gridDim.y) >> 3;                          \
  const int swz  = (id0 & 7) * cpx + (id0 >> 3);                               \
  const int bm   = swz & 255;                                                  \
  const int bn   = swz >> 8;                                                   \
  const int wave = tid >> 6, lane = tid & 63;                                  \
  const int wm   = wave >> 1, wn = wave & 1;                                   \
  const int l15  = lane & 15, quad = lane >> 4;                                \
  const int srow = tid >> 2, skof = (tid & 3) << 3;                            \
  const unsigned short* ga0 = (Aptr) + (size_t)(bm * 128 + srow) * C_ + skof;  \
  const unsigned short* ga1 = ga0 + (size_t)64 * C_;                           \
  const unsigned short* gb0 = (Bptr) + (size_t)(bn * 128 + srow) * C_ + skof;  \
  const unsigned short* gb1 = gb0 + (size_t)64 * C_;                           \
  short* la0 = As + tid * 8;                                                   \
  short* la1 = As + 2048 + tid * 8;                                            \
  short* lb0 = Bs + tid * 8;                                                   \
  short* lb1 = Bs + 2048 + tid * 8;                                            \
  floatx4 acc[4][4];                                                           \
  _Pragma("unroll") for (int i = 0; i < 4; i++)                                \
      _Pragma("unroll") for (int j = 0; j < 4; j++)                            \
          acc[i][j] = {0.f, 0.f, 0.f, 0.f};                                    \
  for (int k0 = 0; k0 < C_; k0 += 32) {                                        \
    glds16(ga0 + k0, la0);                                                     \
    glds16(ga1 + k0, la1);                                                     \
    glds16(gb0 + k0, lb0);                                                     \
    glds16(gb1 + k0, lb1);                                                     \
    __syncthreads();                                                           \
    short8 af[4], bfr[4];                                                      \
    _Pragma("unroll") for (int mi = 0; mi < 4; mi++)                           \
        af[mi] = *(const short8*)&As[(wm * 64 + mi * 16 + l15) * 32 + quad * 8];\
    _Pragma("unroll") for (int ni = 0; ni < 4; ni++)                           \
        bfr[ni] = *(const short8*)&Bs[(wn * 64 + ni * 16 + l15) * 32 + quad * 8];\
    _Pragma("unroll") for (int mi = 0; mi < 4; mi++)                           \
        _Pragma("unroll") for (int ni = 0; ni < 4; ni++)                       \
            acc[mi][ni] = __builtin_amdgcn_mfma_f32_16x16x32_bf16(             \
                af[mi], bfr[ni], acc[mi][ni], 0, 0, 0);                        \
    __syncthreads();                                                           \
  }

// QKV GEMM: A = xb (permuted, linear), B = wb_qkv. M=32768, N=2304.
__global__ __launch_bounds__(256) void qkv_gemm_bf(
    const unsigned short* __restrict__ a,
    const unsigned short* __restrict__ w,
    unsigned short* __restrict__ qkv) {
  GEMM_CORE(a, w)
  const int which = (bn * 128) / 768;          // 0=q 1=k 2=v
  const int jbase = bn * 128 - which * 768;
  unsigned short* dst = qkv + (size_t)which * QKV_PLANE;
#pragma unroll
  for (int mi = 0; mi < 4; mi++) {
#pragma unroll
    for (int r = 0; r < 4; r++) {
      int mg = bm * 128 + wm * 64 + mi * 16 + quad * 4 + r;
      int b = mg >> 12, p = mg & 4095;
      int wdx = p >> 8, t = p & 255;
      size_t base = (size_t)((b * 16 + wdx) * 12) * (NW_ * HD_) + (size_t)t * HD_;
#pragma unroll
      for (int ni = 0; ni < 4; ni++) {
        int jj = jbase + wn * 64 + ni * 16 + l15;
        int h = jj >> 6, d = jj & 63;
        dst[base + (size_t)h * (NW_ * HD_) + d] = f2bf(acc[mi][ni][r]);
      }
    }
  }
}

// Proj GEMM: A = attn_buf bf16 (linear), B = wb_proj. Out f32 + bias.
__global__ __launch_bounds__(256) void proj_gemm_bf(
    const unsigned short* __restrict__ a,
    const unsigned short* __restrict__ w,
    const float* __restrict__ bias,
    float* __restrict__ out) {
  GEMM_CORE(a, w)
#pragma unroll
  for (int mi = 0; mi < 4; mi++) {
#pragma unroll
    for (int r = 0; r < 4; r++) {
      int mg = bm * 128 + wm * 64 + mi * 16 + quad * 4 + r;
      size_t rowb = (size_t)mg * C_;
#pragma unroll
      for (int ni = 0; ni < 4; ni++) {
        int jj = bn * 128 + wn * 64 + ni * 16 + l15;
        out[rowb + jj] = acc[mi][ni][r] + bias[jj];
      }
    }
  }
}

// ---------------------------------------------------------------------------
// MFMA flash attention (unchanged from round 3).
// ---------------------------------------------------------------------------
__global__ __launch_bounds__(512, 2) void attn_mfma(
    const unsigned short* __restrict__ qkv,
    unsigned short* __restrict__ attn_out) {
  const int bwh = blockIdx.x;
  const int tid = threadIdx.x;
  const int wv = tid >> 6, lane = tid & 63;
  const int l15 = lane & 15, quad = lane >> 4;
  const size_t off = (size_t)bwh * (NW_ * HD_);
  const unsigned short* qb = qkv + off;
  const unsigned short* kb = qkv + QKV_PLANE + off;
  const unsigned short* vb = qkv + 2 * QKV_PLANE + off;

  __shared__ short Ks[64 * 72];
  __shared__ short Vt[64 * 72];
  __shared__ short Ps[8][16 * 72];

  short8 bq[2][2];
#pragma unroll
  for (int c = 0; c < 2; c++) {
    int mc = wv + 8 * c;
#pragma unroll
    for (int kc = 0; kc < 2; kc++)
      bq[c][kc] = *(const short8*)(qb + (mc * 16 + l15) * 64 + kc * 32 + quad * 8);
  }

  floatx4 O[2][4];
#pragma unroll
  for (int c = 0; c < 2; c++)
#pragma unroll
    for (int dt = 0; dt < 4; dt++) O[c][dt] = {0.f, 0.f, 0.f, 0.f};
  float m_run[2] = {-1e30f, -1e30f};
  float l_run[2] = {0.f, 0.f};

  const int sr = tid >> 3;
  const int sc = (tid & 7) << 3;

  for (int t = 0; t < 4; t++) {
    __syncthreads();
    {
      short8 kk8 = *(const short8*)(kb + (t * 64 + sr) * 64 + sc);
      *(short8*)&Ks[sr * 72 + sc] = kk8;
      short8 vv8 = *(const short8*)(vb + (t * 64 + sr) * 64 + sc);
#pragma unroll
      for (int j = 0; j < 8; j++) Vt[(sc + j) * 72 + sr] = vv8[j];
    }
    __syncthreads();

#pragma unroll
    for (int c = 0; c < 2; c++) {
      floatx4 st[4];
#pragma unroll
      for (int nt = 0; nt < 4; nt++) {
        short8 ak0 = *(const short8*)&Ks[(nt * 16 + l15) * 72 + quad * 8];
        short8 ak1 = *(const short8*)&Ks[(nt * 16 + l15) * 72 + 32 + quad * 8];
        floatx4 z = {0.f, 0.f, 0.f, 0.f};
        z = __builtin_amdgcn_mfma_f32_16x16x32_bf16(ak0, bq[c][0], z, 0, 0, 0);
        z = __builtin_amdgcn_mfma_f32_16x16x32_bf16(ak1, bq[c][1], z, 0, 0, 0);
        st[nt] = z;
      }
      float s[16];
      float cmax = -1e30f;
#pragma unroll
      for (int nt = 0; nt < 4; nt++)
#pragma unroll
        for (int r = 0; r < 4; r++) {
          float v = st[nt][r] * SCALE_;
          s[nt * 4 + r] = v;
          cmax = fmaxf(cmax, v);
        }
      cmax = fmaxf(cmax, __shfl_xor(cmax, 16));
      cmax = fmaxf(cmax, __shfl_xor(cmax, 32));
      float nm = fmaxf(m_run[c], cmax);
      float alpha = __expf(m_run[c] - nm);
      m_run[c] = nm;
      float psum = 0.f;
#pragma unroll
      for (int j = 0; j < 16; j++) {
        float p = __expf(s[j] - nm);
        s[j] = p;
        psum += p;
      }
      psum += __shfl_xor(psum, 16);
      psum += __shfl_xor(psum, 32);
      l_run[c] = l_run[c] * alpha + psum;
#pragma unroll
      for (int nt = 0; nt < 4; nt++) {
        short4v pv;
        pv[0] = (short)f2bf(s[nt * 4 + 0]);
        pv[1] = (short)f2bf(s[nt * 4 + 1]);
        pv[2] = (short)f2bf(s[nt * 4 + 2]);
        pv[3] = (short)f2bf(s[nt * 4 + 3]);
        *(short4v*)&Ps[wv][l15 * 72 + nt * 16 + quad * 4] = pv;
      }
      float ar[4];
#pragma unroll
      for (int r = 0; r < 4; r++) ar[r] = __shfl(alpha, quad * 4 + r);
#pragma unroll
      for (int dt = 0; dt < 4; dt++)
#pragma unroll
        for (int r = 0; r < 4; r++) O[c][dt][r] *= ar[r];
#pragma unroll
      for (int kc = 0; kc < 2; kc++) {
        short8 ap = *(const short8*)&Ps[wv][l15 * 72 + kc * 32 + quad * 8];
#pragma unroll
        for (int dt = 0; dt < 4; dt++) {
          short8 bv = *(const short8*)&Vt[(dt * 16 + l15) * 72 + kc * 32 + quad * 8];
          O[c][dt] = __builtin_amdgcn_mfma_f32_16x16x32_bf16(ap, bv, O[c][dt], 0, 0, 0);
        }
      }
    }
  }

  int h = bwh % 12, bw = bwh / 12;
  int b = bw >> 4, wdx = bw & 15;
#pragma unroll
  for (int c = 0; c < 2; c++) {
    float linv = 1.f / l_run[c];
    float lr[4];
#pragma unroll
    for (int r = 0; r < 4; r++) lr[r] = __shfl(linv, quad * 4 + r);
    int mc = wv + 8 * c;
#pragma unroll
    for (int r = 0; r < 4; r++) {
      int q = mc * 16 + quad * 4 + r;
      int n = perm_n(wdx, q);
      unsigned short* op = attn_out + ((size_t)(b * N_ + n)) * C_ + h * HD_;
#pragma unroll
      for (int dt = 0; dt < 4; dt++)
        op[dt * 16 + l15] = f2bf(O[c][dt][r] * lr[r]);
    }
  }
}

// ---------------------------------------------------------------------------
// FALLBACK kernels (round-3 style, used only if ws_size < 206 MB)
// ---------------------------------------------------------------------------
__global__ __launch_bounds__(256) void qkv_gemm_f32(
    const float* __restrict__ x,
    const float* __restrict__ w,
    unsigned short* __restrict__ qkv) {
  __shared__ short As[128 * 40];
  __shared__ short Bs[128 * 40];
  const int tid  = threadIdx.x;
  const int bm   = blockIdx.x;
  const int bn   = blockIdx.y;
  const int wave = tid >> 6, lane = tid & 63;
  const int wm   = wave >> 1, wn = wave & 1;
  const int l15  = lane & 15, quad = lane >> 4;
  const int colf  = (tid & 7) << 2;
  const int rbase = tid >> 3;
  size_t aoff[4], boff[4];
#pragma unroll
  for (int i = 0; i < 4; i++) {
    int r = rbase + 32 * i;
    int mg = bm * 128 + r;
    int b = mg >> 12, p = mg & 4095;
    int n = perm_n(p >> 8, p & 255);
    aoff[i] = ((size_t)(b << 12) + (size_t)n) * C_;
    boff[i] = (size_t)(bn * 128 + r) * C_;
  }
  floatx4 acc[4][4];
#pragma unroll
  for (int i = 0; i < 4; i++)
#pragma unroll
    for (int j = 0; j < 4; j++) acc[i][j] = {0.f, 0.f, 0.f, 0.f};
  for (int k0 = 0; k0 < C_; k0 += 32) {
#pragma unroll
    for (int i = 0; i < 4; i++) {
      int r = rbase + 32 * i;
      *(short4v*)&As[r * 40 + colf] = f4bf(*(const floatx4*)(x + aoff[i] + k0 + colf));
      *(short4v*)&Bs[r * 40 + colf] = f4bf(*(const floatx4*)(w + boff[i] + k0 + colf));
    }
    __syncthreads();
    short8 af[4], bfr[4];
#pragma unroll
    for (int mi = 0; mi < 4; mi++)
      af[mi] = *(const short8*)&As[(wm * 64 + mi * 16 + l15) * 40 + quad * 8];
#pragma unroll
    for (int ni = 0; ni < 4; ni++)
      bfr[ni] = *(const short8*)&Bs[(wn * 64 + ni * 16 + l15) * 40 + quad * 8];
#pragma unroll
    for (int mi = 0; mi < 4; mi++)
#pragma unroll
      for (int ni = 0; ni < 4; ni++)
        acc[mi][ni] = __builtin_amdgcn_mfma_f32_16x16x32_bf16(
            af[mi], bfr[ni], acc[mi][ni], 0, 0, 0);
    __syncthreads();
  }
  const int which = (bn * 128) / 768;
  const int jbase = bn * 128 - which * 768;
  unsigned short* dst = qkv + (size_t)which * QKV_PLANE;
#pragma unroll
  for (int mi = 0; mi < 4; mi++) {
#pragma unroll
    for (int r = 0; r < 4; r++) {
      int mg = bm * 128 + wm * 64 + mi * 16 + quad * 4 + r;
      int b = mg >> 12, p = mg & 4095;
      int wdx = p >> 8, t = p & 255;
      size_t base = (size_t)((b * 16 + wdx) * 12) * (NW_ * HD_) + (size_t)t * HD_;
#pragma unroll
      for (int ni = 0; ni < 4; ni++) {
        int jj = jbase + wn * 64 + ni * 16 + l15;
        int h = jj >> 6, d = jj & 63;
        dst[base + (size_t)h * (NW_ * HD_) + d] = f2bf(acc[mi][ni][r]);
      }
    }
  }
}

__global__ __launch_bounds__(256) void proj_gemm_f32(
    const unsigned short* __restrict__ a,
    const float* __restrict__ w,
    const float* __restrict__ bias,
    float* __restrict__ out) {
  __shared__ short As[128 * 40];
  __shared__ short Bs[128 * 40];
  const int tid  = threadIdx.x;
  const int bm   = blockIdx.x;
  const int bn   = blockIdx.y;
  const int wave = tid >> 6, lane = tid & 63;
  const int wm   = wave >> 1, wn = wave & 1;
  const int l15  = lane & 15, quad = lane >> 4;
  const int c0 = tid, c1 = tid + 256;
  const int r0 = c0 >> 2, kc0 = (c0 & 3) << 3;
  const int r1 = c1 >> 2, kc1 = (c1 & 3) << 3;
  const size_t a0 = (size_t)(bm * 128 + r0) * C_;
  const size_t a1 = (size_t)(bm * 128 + r1) * C_;
  const int colf  = (tid & 7) << 2;
  const int rbase = tid >> 3;
  size_t boff[4];
#pragma unroll
  for (int i = 0; i < 4; i++)
    boff[i] = (size_t)(bn * 128 + rbase + 32 * i) * C_;
  floatx4 acc[4][4];
#pragma unroll
  for (int i = 0; i < 4; i++)
#pragma unroll
    for (int j = 0; j < 4; j++) acc[i][j] = {0.f, 0.f, 0.f, 0.f};
  for (int k0 = 0; k0 < C_; k0 += 32) {
    *(short8*)&As[r0 * 40 + kc0] = *(const short8*)(a + a0 + k0 + kc0);
    *(short8*)&As[r1 * 40 + kc1] = *(const short8*)(a + a1 + k0 + kc1);
#pragma unroll
    for (int i = 0; i < 4; i++) {
      int r = rbase + 32 * i;
      *(short4v*)&Bs[r * 40 + colf] = f4bf(*(const floatx4*)(w + boff[i] + k0 + colf));
    }
    __syncthreads();
    short8 af[4], bfr[4];
#pragma unroll
    for (int mi = 0; mi < 4; mi++)
      af[mi] = *(const short8*)&As[(wm * 64 + mi * 16 + l15) * 40 + quad * 8];
#pragma unroll
    for (int ni = 0; ni < 4; ni++)
      bfr[ni] = *(const short8*)&Bs[(wn * 64 + ni * 16 + l15) * 40 + quad * 8];
#pragma unroll
    for (int mi = 0; mi < 4; mi++)
#pragma unroll
      for (int ni = 0; ni < 4; ni++)
        acc[mi][ni] = __builtin_amdgcn_mfma_f32_16x16x32_bf16(
            af[mi], bfr[ni], acc[mi][ni], 0, 0, 0);
    __syncthreads();
  }
#pragma unroll
  for (int mi = 0; mi < 4; mi++) {
#pragma unroll
    for (int r = 0; r < 4; r++) {
      int mg = bm * 128 + wm * 64 + mi * 16 + quad * 4 + r;
      size_t rowb = (size_t)mg * C_;
#pragma unroll
      for (int ni = 0; ni < 4; ni++) {
        int jj = bn * 128 + wn * 64 + ni * 16 + l15;
        out[rowb + jj] = acc[mi][ni][r] + bias[jj];
      }
    }
  }
}

extern "C" void kernel_launch(void* const* d_in, const int* in_sizes, int n_in,
                              void* d_out, int out_size, void* d_ws, size_t ws_size,
                              hipStream_t stream) {
  const float* x  = (const float*)d_in[0];
  const float* qw = (const float*)d_in[1];
  const float* pw = (const float*)d_in[2];
  const float* pb = (const float*)d_in[3];
  float* out = (float*)d_out;
  unsigned short* ws = (unsigned short*)d_ws;

  unsigned short* xb       = ws;                    // plane 0 (xb, then attn_buf)
  unsigned short* qkv_buf  = ws + QKV_PLANE;        // planes 1..3 = q,k,v
  unsigned short* attn_buf = ws;                    // reuses plane 0
  unsigned short* wb_qkv   = ws + 4 * QKV_PLANE;                  // 2304*768
  unsigned short* wb_proj  = wb_qkv + (size_t)2304 * 768;         // 768*768

  const size_t need = (4 * QKV_PLANE + (size_t)2304 * 768 + (size_t)768 * 768) * 2;
  if (ws_size >= need) {
    conv_x<<<dim3(B_ * N_), dim3(192), 0, stream>>>(x, xb);
    conv_w<<<dim3(3072), dim3(192), 0, stream>>>(qw, pw, wb_qkv, wb_proj);
    qkv_gemm_bf<<<dim3(256, 18), dim3(256), 0, stream>>>(xb, wb_qkv, qkv_buf);
    attn_mfma<<<dim3(1536), dim3(512), 0, stream>>>(qkv_buf, attn_buf);
    proj_gemm_bf<<<dim3(256, 6), dim3(256), 0, stream>>>(attn_buf, wb_proj, pb, out);
  } else {
    qkv_gemm_f32<<<dim3(256, 18), dim3(256), 0, stream>>>(x, qw, qkv_buf);
    attn_mfma<<<dim3(1536), dim3(512), 0, stream>>>(qkv_buf, attn_buf);
    proj_gemm_f32<<<dim3(256, 6), dim3(256), 0, stream>>>(attn_buf, pw, pb, out);
  }
}

// Round 2
// 438.995 us; speedup vs baseline: 1.1033x; 1.1033x over previous
//
#include <hip/hip_runtime.h>
#include <hip/hip_bf16.h>

// ===========================================================================
// WindowedAttention: B=8, N=4096, C=768, H=12, HD=64, W=16 -> 16 windows x 256
// I/O float32; internal bf16 MFMA, fp32 accumulate.
//   k0 conv_x/conv_w: f32 -> bf16 pre-pass; x written WINDOW-PERMUTED.
//   k1 qkv_gemm_bf8 : 256x256 8-phase schedule (T2+T3+T4+T5), BK=64, 512 thr
//   k2 attn_mfma    : flash-style per (b,w,h), unchanged.
//   k3 proj_gemm_bf8: same 8-phase core, epilogue f32 + bias -> d_out
// R1 change: both GEMMs ported from m97 2-phase 128^2 (623 TF measured,
// MfmaUtil 26%) to the 8-phase 256^2 template: counted vmcnt(4) at phases
// 4/8 only, granule-XOR LDS swizzle (source-preswizzled for global_load_lds),
// setprio around MFMA clusters. T1 block swizzle reverted (L3-fit regression).
// ===========================================================================

using short8  = __attribute__((ext_vector_type(8))) short;
using short4v = __attribute__((ext_vector_type(4))) short;
using floatx4 = __attribute__((ext_vector_type(4))) float;

#define B_    8
#define N_    4096
#define C_    768
#define H_    12
#define HD_   64
#define NW_   256
#define SCALE_ 0.125f
#define QKV_PLANE ((size_t)25165824)   // B*16*12*256*64 == B*N*C

__device__ __forceinline__ float bf2f(unsigned short u) {
  union { unsigned int i; float f; } c; c.i = ((unsigned int)u) << 16; return c.f;
}
__device__ __forceinline__ unsigned short f2bf(float f) {
  unsigned int u = __float_as_uint(f);
  u += 0x7fffu + ((u >> 16) & 1u);   // RNE
  return (unsigned short)(u >> 16);
}
__device__ __forceinline__ short4v f4bf(floatx4 f) {
  short4v s;
  s[0] = (short)f2bf(f[0]); s[1] = (short)f2bf(f[1]);
  s[2] = (short)f2bf(f[2]); s[3] = (short)f2bf(f[3]);
  return s;
}
__device__ __forceinline__ int perm_n(int w, int t) {
  int rb = w >> 2, cb = w & 3, ri = t >> 4, ci = t & 15;
  return ((rb << 4) + ri) * 64 + (cb << 4) + ci;
}
__device__ __forceinline__ void glds16(const unsigned short* g, short* l) {
  __builtin_amdgcn_global_load_lds(
      (const __attribute__((address_space(1))) unsigned int*)g,
      (__attribute__((address_space(3))) unsigned int*)l, 16, 0, 0);
}

// ---------------------------------------------------------------------------
// conv_x: x f32 [b][n][c] -> xb bf16 [b][p][c] with p in window-permuted order
// ---------------------------------------------------------------------------
__global__ __launch_bounds__(192) void conv_x(
    const float* __restrict__ x, unsigned short* __restrict__ xb) {
  int row = blockIdx.x;               // b*4096 + p
  int b = row >> 12, p = row & 4095;
  int n = perm_n(p >> 8, p & 255);
  const float* src = x + ((size_t)(b << 12) + (size_t)n) * C_;
  unsigned short* dst = xb + (size_t)row * C_;
  int c = threadIdx.x << 2;
  *(short4v*)(dst + c) = f4bf(*(const floatx4*)(src + c));
}

// conv_w: qkv_w (2304x768) and proj_w (768x768) f32 -> bf16
__global__ __launch_bounds__(192) void conv_w(
    const float* __restrict__ qw, const float* __restrict__ pw,
    unsigned short* __restrict__ wq, unsigned short* __restrict__ wp) {
  int row = blockIdx.x;
  const float* src; unsigned short* dst;
  if (row < 2304) { src = qw + (size_t)row * C_; dst = wq + (size_t)row * C_; }
  else { src = pw + (size_t)(row - 2304) * C_; dst = wp + (size_t)(row - 2304) * C_; }
  int c = threadIdx.x << 2;
  *(short4v*)(dst + c) = f4bf(*(const floatx4*)(src + c));
}

// ---------------------------------------------------------------------------
// 8-phase 256x256 bf16 GEMM core (plain-HIP port of the HK cdna4 schedule).
// 512 threads = 8 waves (2M x 4N); per-wave output 128x64.
// LDS 128 KiB: P (K-step even) at 0, Q (odd) at 32K shorts.
//   region layout per buffer: A[2 halves][128 rows][64 k] then B same.
// Granule swizzle: 16B granule g at row r stored at g^(r&7); global source
// pre-swizzled so global_load_lds dest stays lane-linear (rule 21).
// Phases: ph1-4 compute K-step t from P (quadrants of 32 rows), ph5-8 step
// t+1 from Q. Staging (1 half-tile = 2 glds16/thread per phase):
//   ph1/2: Q.A <- A(t+1)   [Q.A freed at prev ph8]
//   ph3/4: P.B <- B(t+2)   [P.B read only in ph1]
//   ph5/6: P.A <- A(t+2)   [P.A freed at ph4]
//   ph7/8: Q.B <- B(t+3)   [Q.B read only in ph5]
// vmcnt(4) at ph4 (guarantees Q.A + older done) and ph8 (P fully done).
// K-steps >= 12 stage clamped junk into regions never read again.
// ---------------------------------------------------------------------------
#define LPA 0
#define LPB 16384
#define LQA 32768
#define LQB 49152

#define STAGE8(gp, ldsbase, ksk) {                                             \
    int kc_ = (ksk) < C_ ? (ksk) : 0;                                          \
    glds16((gp) + (size_t)arow * C_ + kc_ + (sgran << 3),                      \
           L + (ldsbase) + tid * 8);                                           \
    glds16((gp) + (size_t)(arow + 64) * C_ + kc_ + (sgran << 3),               \
           L + (ldsbase) + 4096 + tid * 8);                                    \
  }

#define PH8(q, AB, BB, LOADB, STG_STMT, WV) {                                  \
    if (LOADB) {                                                               \
      _Pragma("unroll") for (int n = 0; n < 4; n++)                            \
        _Pragma("unroll") for (int kk = 0; kk < 2; kk++)                       \
          bq[n][kk] = *(const short8*)&L[(BB) + rdB + n * 1024 +               \
                                          (((kk * 4 + quad) ^ swq) << 3)];     \
    }                                                                          \
    short8 a0k0 = *(const short8*)&L[(AB) + rdA + (2*(q))*1024 +               \
                                      (((quad) ^ swq) << 3)];                  \
    short8 a0k1 = *(const short8*)&L[(AB) + rdA + (2*(q))*1024 +               \
                                      (((4 + quad) ^ swq) << 3)];              \
    short8 a1k0 = *(const short8*)&L[(AB) + rdA + (2*(q)+1)*1024 +             \
                                      (((quad) ^ swq) << 3)];                  \
    short8 a1k1 = *(const short8*)&L[(AB) + rdA + (2*(q)+1)*1024 +             \
                                      (((4 + quad) ^ swq) << 3)];              \
    STG_STMT;                                                                  \
    asm volatile("s_barrier" ::: "memory");                                    \
    asm volatile("s_waitcnt lgkmcnt(0)" ::: "memory");                         \
    __builtin_amdgcn_sched_barrier(0);                                         \
    __builtin_amdgcn_s_setprio(1);                                             \
    _Pragma("unroll") for (int n = 0; n < 4; n++) {                            \
      acc[2*(q)][n]   = __builtin_amdgcn_mfma_f32_16x16x32_bf16(               \
          a0k0, bq[n][0], acc[2*(q)][n], 0, 0, 0);                             \
      acc[2*(q)+1][n] = __builtin_amdgcn_mfma_f32_16x16x32_bf16(               \
          a1k0, bq[n][0], acc[2*(q)+1][n], 0, 0, 0);                           \
      acc[2*(q)][n]   = __builtin_amdgcn_mfma_f32_16x16x32_bf16(               \
          a0k1, bq[n][1], acc[2*(q)][n], 0, 0, 0);                             \
      acc[2*(q)+1][n] = __builtin_amdgcn_mfma_f32_16x16x32_bf16(               \
          a1k1, bq[n][1], acc[2*(q)+1][n], 0, 0, 0);                           \
    }                                                                          \
    __builtin_amdgcn_s_setprio(0);                                             \
    if (WV) { asm volatile("s_waitcnt vmcnt(4)" ::: "memory"); }               \
    asm volatile("s_barrier" ::: "memory");                                    \
  }

#define GEMM8_CORE(Aptr, Bptr)                                                 \
  __shared__ short L[65536];                                                   \
  const int tid  = threadIdx.x;                                                \
  const int bm   = blockIdx.x;                                                 \
  const int bn   = blockIdx.y;                                                 \
  const int wave = tid >> 6, lane = tid & 63;                                  \
  const int wm   = wave >> 2, wn = wave & 3;                                   \
  const int l15  = lane & 15, quad = lane >> 4;                                \
  const int swq  = l15 & 7;                                                    \
  const int sgran = (tid & 7) ^ ((tid >> 3) & 7);                              \
  const int arow  = tid >> 3;                                                  \
  const unsigned short* gA = (Aptr) + (size_t)(bm * 256) * C_;                 \
  const unsigned short* gB = (Bptr) + (size_t)(bn * 256) * C_;                 \
  const unsigned short* gA1 = gA + (size_t)128 * C_;                           \
  const unsigned short* gB1 = gB + (size_t)128 * C_;                           \
  const int rdA = wm * 8192 + l15 * 64;                                        \
  const int rdB = (wn >> 1) * 8192 + ((wn & 1) * 64 + l15) * 64;               \
  floatx4 acc[8][4];                                                           \
  short8 bq[4][2];                                                             \
  _Pragma("unroll") for (int i = 0; i < 8; i++)                                \
      _Pragma("unroll") for (int j = 0; j < 4; j++)                            \
          acc[i][j] = {0.f, 0.f, 0.f, 0.f};                                    \
  /* prologue: P <- K-step 0 (A+B), Q.B <- K-step 1 */                         \
  STAGE8(gA,  LPA,        0); STAGE8(gA1, LPA + 8192, 0);                      \
  STAGE8(gB,  LPB,        0); STAGE8(gB1, LPB + 8192, 0);                      \
  STAGE8(gB,  LQB,       64); STAGE8(gB1, LQB + 8192, 64);                     \
  asm volatile("s_waitcnt vmcnt(4)" ::: "memory");                             \
  asm volatile("s_barrier" ::: "memory");                                      \
  for (int it = 0; it < 6; it++) {                                             \
    const int t  = it * 2;                                                     \
    const int kA1 = (t + 1) * 64;                                              \
    const int kN2 = (t + 2) * 64;                                              \
    const int kN3 = (t + 3) * 64;                                              \
    PH8(0, LPA, LPB, 1, STAGE8(gA,  LQA,        kA1), 0)                       \
    PH8(1, LPA, LPB, 0, STAGE8(gA1, LQA + 8192, kA1), 0)                       \
    PH8(2, LPA, LPB, 0, STAGE8(gB,  LPB,        kN2), 0)                       \
    PH8(3, LPA, LPB, 0, STAGE8(gB1, LPB + 8192, kN2), 1)                       \
    PH8(0, LQA, LQB, 1, STAGE8(gA,  LPA,        kN2), 0)                       \
    PH8(1, LQA, LQB, 0, STAGE8(gA1, LPA + 8192, kN2), 0)                       \
    PH8(2, LQA, LQB, 0, STAGE8(gB,  LQB,        kN3), 0)                       \
    PH8(3, LQA, LQB, 0, STAGE8(gB1, LQB + 8192, kN3), 1)                       \
  }

// QKV GEMM: A = xb (permuted, linear), B = wb_qkv. M=32768, N=2304.
// Grid (128, 9); bn 0-2 -> q, 3-5 -> k, 6-8 -> v (768 = 3*256).
__global__ __launch_bounds__(512, 2) void qkv_gemm_bf8(
    const unsigned short* __restrict__ a,
    const unsigned short* __restrict__ w,
    unsigned short* __restrict__ qkv) {
  GEMM8_CORE(a, w)
  const int which = bn / 3;
  const int jbase = (bn - which * 3) * 256;
  unsigned short* dst = qkv + (size_t)which * QKV_PLANE;
#pragma unroll
  for (int mi = 0; mi < 8; mi++) {
#pragma unroll
    for (int r = 0; r < 4; r++) {
      int mg = bm * 256 + wm * 128 + mi * 16 + quad * 4 + r;
      int b = mg >> 12, p = mg & 4095;
      int wdx = p >> 8, tt = p & 255;
      size_t base = (size_t)((b * 16 + wdx) * 12) * (NW_ * HD_) + (size_t)tt * HD_;
#pragma unroll
      for (int ni = 0; ni < 4; ni++) {
        int jj = jbase + wn * 64 + ni * 16 + l15;
        int h = jj >> 6, d = jj & 63;
        dst[base + (size_t)h * (NW_ * HD_) + d] = f2bf(acc[mi][ni][r]);
      }
    }
  }
  asm volatile("s_waitcnt vmcnt(0)" ::: "memory");
}

// Proj GEMM: A = attn_buf bf16 (linear), B = wb_proj. Out f32 + bias.
// Grid (128, 3).
__global__ __launch_bounds__(512, 2) void proj_gemm_bf8(
    const unsigned short* __restrict__ a,
    const unsigned short* __restrict__ w,
    const float* __restrict__ bias,
    float* __restrict__ out) {
  GEMM8_CORE(a, w)
#pragma unroll
  for (int mi = 0; mi < 8; mi++) {
#pragma unroll
    for (int r = 0; r < 4; r++) {
      int mg = bm * 256 + wm * 128 + mi * 16 + quad * 4 + r;
      size_t rowb = (size_t)mg * C_;
#pragma unroll
      for (int ni = 0; ni < 4; ni++) {
        int jj = bn * 256 + wn * 64 + ni * 16 + l15;
        out[rowb + jj] = acc[mi][ni][r] + bias[jj];
      }
    }
  }
  asm volatile("s_waitcnt vmcnt(0)" ::: "memory");
}

// ---------------------------------------------------------------------------
// MFMA flash attention (unchanged).
// ---------------------------------------------------------------------------
__global__ __launch_bounds__(512, 2) void attn_mfma(
    const unsigned short* __restrict__ qkv,
    unsigned short* __restrict__ attn_out) {
  const int bwh = blockIdx.x;
  const int tid = threadIdx.x;
  const int wv = tid >> 6, lane = tid & 63;
  const int l15 = lane & 15, quad = lane >> 4;
  const size_t off = (size_t)bwh * (NW_ * HD_);
  const unsigned short* qb = qkv + off;
  const unsigned short* kb = qkv + QKV_PLANE + off;
  const unsigned short* vb = qkv + 2 * QKV_PLANE + off;

  __shared__ short Ks[64 * 72];
  __shared__ short Vt[64 * 72];
  __shared__ short Ps[8][16 * 72];

  short8 bq[2][2];
#pragma unroll
  for (int c = 0; c < 2; c++) {
    int mc = wv + 8 * c;
#pragma unroll
    for (int kc = 0; kc < 2; kc++)
      bq[c][kc] = *(const short8*)(qb + (mc * 16 + l15) * 64 + kc * 32 + quad * 8);
  }

  floatx4 O[2][4];
#pragma unroll
  for (int c = 0; c < 2; c++)
#pragma unroll
    for (int dt = 0; dt < 4; dt++) O[c][dt] = {0.f, 0.f, 0.f, 0.f};
  float m_run[2] = {-1e30f, -1e30f};
  float l_run[2] = {0.f, 0.f};

  const int sr = tid >> 3;
  const int sc = (tid & 7) << 3;

  for (int t = 0; t < 4; t++) {
    __syncthreads();
    {
      short8 kk8 = *(const short8*)(kb + (t * 64 + sr) * 64 + sc);
      *(short8*)&Ks[sr * 72 + sc] = kk8;
      short8 vv8 = *(const short8*)(vb + (t * 64 + sr) * 64 + sc);
#pragma unroll
      for (int j = 0; j < 8; j++) Vt[(sc + j) * 72 + sr] = vv8[j];
    }
    __syncthreads();

#pragma unroll
    for (int c = 0; c < 2; c++) {
      floatx4 st[4];
#pragma unroll
      for (int nt = 0; nt < 4; nt++) {
        short8 ak0 = *(const short8*)&Ks[(nt * 16 + l15) * 72 + quad * 8];
        short8 ak1 = *(const short8*)&Ks[(nt * 16 + l15) * 72 + 32 + quad * 8];
        floatx4 z = {0.f, 0.f, 0.f, 0.f};
        z = __builtin_amdgcn_mfma_f32_16x16x32_bf16(ak0, bq[c][0], z, 0, 0, 0);
        z = __builtin_amdgcn_mfma_f32_16x16x32_bf16(ak1, bq[c][1], z, 0, 0, 0);
        st[nt] = z;
      }
      float s[16];
      float cmax = -1e30f;
#pragma unroll
      for (int nt = 0; nt < 4; nt++)
#pragma unroll
        for (int r = 0; r < 4; r++) {
          float v = st[nt][r] * SCALE_;
          s[nt * 4 + r] = v;
          cmax = fmaxf(cmax, v);
        }
      cmax = fmaxf(cmax, __shfl_xor(cmax, 16));
      cmax = fmaxf(cmax, __shfl_xor(cmax, 32));
      float nm = fmaxf(m_run[c], cmax);
      float alpha = __expf(m_run[c] - nm);
      m_run[c] = nm;
      float psum = 0.f;
#pragma unroll
      for (int j = 0; j < 16; j++) {
        float p = __expf(s[j] - nm);
        s[j] = p;
        psum += p;
      }
      psum += __shfl_xor(psum, 16);
      psum += __shfl_xor(psum, 32);
      l_run[c] = l_run[c] * alpha + psum;
#pragma unroll
      for (int nt = 0; nt < 4; nt++) {
        short4v pv;
        pv[0] = (short)f2bf(s[nt * 4 + 0]);
        pv[1] = (short)f2bf(s[nt * 4 + 1]);
        pv[2] = (short)f2bf(s[nt * 4 + 2]);
        pv[3] = (short)f2bf(s[nt * 4 + 3]);
        *(short4v*)&Ps[wv][l15 * 72 + nt * 16 + quad * 4] = pv;
      }
      float ar[4];
#pragma unroll
      for (int r = 0; r < 4; r++) ar[r] = __shfl(alpha, quad * 4 + r);
#pragma unroll
      for (int dt = 0; dt < 4; dt++)
#pragma unroll
        for (int r = 0; r < 4; r++) O[c][dt][r] *= ar[r];
#pragma unroll
      for (int kc = 0; kc < 2; kc++) {
        short8 ap = *(const short8*)&Ps[wv][l15 * 72 + kc * 32 + quad * 8];
#pragma unroll
        for (int dt = 0; dt < 4; dt++) {
          short8 bv = *(const short8*)&Vt[(dt * 16 + l15) * 72 + kc * 32 + quad * 8];
          O[c][dt] = __builtin_amdgcn_mfma_f32_16x16x32_bf16(ap, bv, O[c][dt], 0, 0, 0);
        }
      }
    }
  }

  int h = bwh % 12, bw = bwh / 12;
  int b = bw >> 4, wdx = bw & 15;
#pragma unroll
  for (int c = 0; c < 2; c++) {
    float linv = 1.f / l_run[c];
    float lr[4];
#pragma unroll
    for (int r = 0; r < 4; r++) lr[r] = __shfl(linv, quad * 4 + r);
    int mc = wv + 8 * c;
#pragma unroll
    for (int r = 0; r < 4; r++) {
      int q = mc * 16 + quad * 4 + r;
      int n = perm_n(wdx, q);
      unsigned short* op = attn_out + ((size_t)(b * N_ + n)) * C_ + h * HD_;
#pragma unroll
      for (int dt = 0; dt < 4; dt++)
        op[dt * 16 + l15] = f2bf(O[c][dt][r] * lr[r]);
    }
  }
}

// ---------------------------------------------------------------------------
// FALLBACK kernels (used only if ws_size < 206 MB)
// ---------------------------------------------------------------------------
__global__ __launch_bounds__(256) void qkv_gemm_f32(
    const float* __restrict__ x,
    const float* __restrict__ w,
    unsigned short* __restrict__ qkv) {
  __shared__ short As[128 * 40];
  __shared__ short Bs[128 * 40];
  const int tid  = threadIdx.x;
  const int bm   = blockIdx.x;
  const int bn   = blockIdx.y;
  const int wave = tid >> 6, lane = tid & 63;
  const int wm   = wave >> 1, wn = wave & 1;
  const int l15  = lane & 15, quad = lane >> 4;
  const int colf  = (tid & 7) << 2;
  const int rbase = tid >> 3;
  size_t aoff[4], boff[4];
#pragma unroll
  for (int i = 0; i < 4; i++) {
    int r = rbase + 32 * i;
    int mg = bm * 128 + r;
    int b = mg >> 12, p = mg & 4095;
    int n = perm_n(p >> 8, p & 255);
    aoff[i] = ((size_t)(b << 12) + (size_t)n) * C_;
    boff[i] = (size_t)(bn * 128 + r) * C_;
  }
  floatx4 acc[4][4];
#pragma unroll
  for (int i = 0; i < 4; i++)
#pragma unroll
    for (int j = 0; j < 4; j++) acc[i][j] = {0.f, 0.f, 0.f, 0.f};
  for (int k0 = 0; k0 < C_; k0 += 32) {
#pragma unroll
    for (int i = 0; i < 4; i++) {
      int r = rbase + 32 * i;
      *(short4v*)&As[r * 40 + colf] = f4bf(*(const floatx4*)(x + aoff[i] + k0 + colf));
      *(short4v*)&Bs[r * 40 + colf] = f4bf(*(const floatx4*)(w + boff[i] + k0 + colf));
    }
    __syncthreads();
    short8 af[4], bfr[4];
#pragma unroll
    for (int mi = 0; mi < 4; mi++)
      af[mi] = *(const short8*)&As[(wm * 64 + mi * 16 + l15) * 40 + quad * 8];
#pragma unroll
    for (int ni = 0; ni < 4; ni++)
      bfr[ni] = *(const short8*)&Bs[(wn * 64 + ni * 16 + l15) * 40 + quad * 8];
#pragma unroll
    for (int mi = 0; mi < 4; mi++)
#pragma unroll
      for (int ni = 0; ni < 4; ni++)
        acc[mi][ni] = __builtin_amdgcn_mfma_f32_16x16x32_bf16(
            af[mi], bfr[ni], acc[mi][ni], 0, 0, 0);
    __syncthreads();
  }
  const int which = (bn * 128) / 768;
  const int jbase = bn * 128 - which * 768;
  unsigned short* dst = qkv + (size_t)which * QKV_PLANE;
#pragma unroll
  for (int mi = 0; mi < 4; mi++) {
#pragma unroll
    for (int r = 0; r < 4; r++) {
      int mg = bm * 128 + wm * 64 + mi * 16 + quad * 4 + r;
      int b = mg >> 12, p = mg & 4095;
      int wdx = p >> 8, t = p & 255;
      size_t base = (size_t)((b * 16 + wdx) * 12) * (NW_ * HD_) + (size_t)t * HD_;
#pragma unroll
      for (int ni = 0; ni < 4; ni++) {
        int jj = jbase + wn * 64 + ni * 16 + l15;
        int h = jj >> 6, d = jj & 63;
        dst[base + (size_t)h * (NW_ * HD_) + d] = f2bf(acc[mi][ni][r]);
      }
    }
  }
}

__global__ __launch_bounds__(256) void proj_gemm_f32(
    const unsigned short* __restrict__ a,
    const float* __restrict__ w,
    const float* __restrict__ bias,
    float* __restrict__ out) {
  __shared__ short As[128 * 40];
  __shared__ short Bs[128 * 40];
  const int tid  = threadIdx.x;
  const int bm   = blockIdx.x;
  const int bn   = blockIdx.y;
  const int wave = tid >> 6, lane = tid & 63;
  const int wm   = wave >> 1, wn = wave & 1;
  const int l15  = lane & 15, quad = lane >> 4;
  const int c0 = tid, c1 = tid + 256;
  const int r0 = c0 >> 2, kc0 = (c0 & 3) << 3;
  const int r1 = c1 >> 2, kc1 = (c1 & 3) << 3;
  const size_t a0 = (size_t)(bm * 128 + r0) * C_;
  const size_t a1 = (size_t)(bm * 128 + r1) * C_;
  const int colf  = (tid & 7) << 2;
  const int rbase = tid >> 3;
  size_t boff[4];
#pragma unroll
  for (int i = 0; i < 4; i++)
    boff[i] = (size_t)(bn * 128 + rbase + 32 * i) * C_;
  floatx4 acc[4][4];
#pragma unroll
  for (int i = 0; i < 4; i++)
#pragma unroll
    for (int j = 0; j < 4; j++) acc[i][j] = {0.f, 0.f, 0.f, 0.f};
  for (int k0 = 0; k0 < C_; k0 += 32) {
    *(short8*)&As[r0 * 40 + kc0] = *(const short8*)(a + a0 + k0 + kc0);
    *(short8*)&As[r1 * 40 + kc1] = *(const short8*)(a + a1 + k0 + kc1);
#pragma unroll
    for (int i = 0; i < 4; i++) {
      int r = rbase + 32 * i;
      *(short4v*)&Bs[r * 40 + colf] = f4bf(*(const floatx4*)(w + boff[i] + k0 + colf));
    }
    __syncthreads();
    short8 af[4], bfr[4];
#pragma unroll
    for (int mi = 0; mi < 4; mi++)
      af[mi] = *(const short8*)&As[(wm * 64 + mi * 16 + l15) * 40 + quad * 8];
#pragma unroll
    for (int ni = 0; ni < 4; ni++)
      bfr[ni] = *(const short8*)&Bs[(wn * 64 + ni * 16 + l15) * 40 + quad * 8];
#pragma unroll
    for (int mi = 0; mi < 4; mi++)
#pragma unroll
      for (int ni = 0; ni < 4; ni++)
        acc[mi][ni] = __builtin_amdgcn_mfma_f32_16x16x32_bf16(
            af[mi], bfr[ni], acc[mi][ni], 0, 0, 0);
    __syncthreads();
  }
#pragma unroll
  for (int mi = 0; mi < 4; mi++) {
#pragma unroll
    for (int r = 0; r < 4; r++) {
      int mg = bm * 128 + wm * 64 + mi * 16 + quad * 4 + r;
      size_t rowb = (size_t)mg * C_;
#pragma unroll
      for (int ni = 0; ni < 4; ni++) {
        int jj = bn * 128 + wn * 64 + ni * 16 + l15;
        out[rowb + jj] = acc[mi][ni][r] + bias[jj];
      }
    }
  }
}

extern "C" void kernel_launch(void* const* d_in, const int* in_sizes, int n_in,
                              void* d_out, int out_size, void* d_ws, size_t ws_size,
                              hipStream_t stream) {
  const float* x  = (const float*)d_in[0];
  const float* qw = (const float*)d_in[1];
  const float* pw = (const float*)d_in[2];
  const float* pb = (const float*)d_in[3];
  float* out = (float*)d_out;
  unsigned short* ws = (unsigned short*)d_ws;

  unsigned short* xb       = ws;                    // plane 0 (xb, then attn_buf)
  unsigned short* qkv_buf  = ws + QKV_PLANE;        // planes 1..3 = q,k,v
  unsigned short* attn_buf = ws;                    // reuses plane 0
  unsigned short* wb_qkv   = ws + 4 * QKV_PLANE;                  // 2304*768
  unsigned short* wb_proj  = wb_qkv + (size_t)2304 * 768;         // 768*768

  const size_t need = (4 * QKV_PLANE + (size_t)2304 * 768 + (size_t)768 * 768) * 2;
  if (ws_size >= need) {
    conv_x<<<dim3(B_ * N_), dim3(192), 0, stream>>>(x, xb);
    conv_w<<<dim3(3072), dim3(192), 0, stream>>>(qw, pw, wb_qkv, wb_proj);
    qkv_gemm_bf8<<<dim3(128, 9), dim3(512), 0, stream>>>(xb, wb_qkv, qkv_buf);
    attn_mfma<<<dim3(1536), dim3(512), 0, stream>>>(qkv_buf, attn_buf);
    proj_gemm_bf8<<<dim3(128, 3), dim3(512), 0, stream>>>(attn_buf, wb_proj, pb, out);
  } else {
    qkv_gemm_f32<<<dim3(256, 18), dim3(256), 0, stream>>>(x, qw, qkv_buf);
    attn_mfma<<<dim3(1536), dim3(512), 0, stream>>>(qkv_buf, attn_buf);
    proj_gemm_f32<<<dim3(256, 6), dim3(256), 0, stream>>>(attn_buf, pw, pb, out);
  }
}

// Round 3
// 424.408 us; speedup vs baseline: 1.1412x; 1.0344x over previous
//
#include <hip/hip_runtime.h>
#include <hip/hip_bf16.h>

// ===========================================================================
// WindowedAttention: B=8, N=4096, C=768, H=12, HD=64, W=16 -> 16 windows x 256
// I/O float32; internal bf16 MFMA, fp32 accumulate.
//   k0 conv_x/conv_w: f32 -> bf16 pre-pass; x written WINDOW-PERMUTED.
//   k1 qkv_gemm_bf8 : 256x256 8-phase (VERIFIED R2: 132us, MfmaUtil 37%, 0 bk)
//   k2 attn_mfma    : flash-style; R3: double-buffered K/V with early global
//                     load issue (T14) + setprio (T5); 1 barrier/iter.
//   k3 proj_gemm_bf8: R3: 128x256 tile 8-phase, grid (256,3)=768 blocks = 3.0
//                     exact rounds (was 256x256 grid 384 = 1.5 rounds, ~33%
//                     CU-idle quantization).
// ===========================================================================

using short8  = __attribute__((ext_vector_type(8))) short;
using short4v = __attribute__((ext_vector_type(4))) short;
using floatx4 = __attribute__((ext_vector_type(4))) float;

#define B_    8
#define N_    4096
#define C_    768
#define H_    12
#define HD_   64
#define NW_   256
#define SCALE_ 0.125f
#define QKV_PLANE ((size_t)25165824)   // B*16*12*256*64 == B*N*C

__device__ __forceinline__ float bf2f(unsigned short u) {
  union { unsigned int i; float f; } c; c.i = ((unsigned int)u) << 16; return c.f;
}
__device__ __forceinline__ unsigned short f2bf(float f) {
  unsigned int u = __float_as_uint(f);
  u += 0x7fffu + ((u >> 16) & 1u);   // RNE
  return (unsigned short)(u >> 16);
}
__device__ __forceinline__ short4v f4bf(floatx4 f) {
  short4v s;
  s[0] = (short)f2bf(f[0]); s[1] = (short)f2bf(f[1]);
  s[2] = (short)f2bf(f[2]); s[3] = (short)f2bf(f[3]);
  return s;
}
__device__ __forceinline__ int perm_n(int w, int t) {
  int rb = w >> 2, cb = w & 3, ri = t >> 4, ci = t & 15;
  return ((rb << 4) + ri) * 64 + (cb << 4) + ci;
}
__device__ __forceinline__ void glds16(const unsigned short* g, short* l) {
  __builtin_amdgcn_global_load_lds(
      (const __attribute__((address_space(1))) unsigned int*)g,
      (__attribute__((address_space(3))) unsigned int*)l, 16, 0, 0);
}

// ---------------------------------------------------------------------------
// conv_x: x f32 [b][n][c] -> xb bf16 [b][p][c] with p in window-permuted order
// ---------------------------------------------------------------------------
__global__ __launch_bounds__(192) void conv_x(
    const float* __restrict__ x, unsigned short* __restrict__ xb) {
  int row = blockIdx.x;               // b*4096 + p
  int b = row >> 12, p = row & 4095;
  int n = perm_n(p >> 8, p & 255);
  const float* src = x + ((size_t)(b << 12) + (size_t)n) * C_;
  unsigned short* dst = xb + (size_t)row * C_;
  int c = threadIdx.x << 2;
  *(short4v*)(dst + c) = f4bf(*(const floatx4*)(src + c));
}

// conv_w: qkv_w (2304x768) and proj_w (768x768) f32 -> bf16
__global__ __launch_bounds__(192) void conv_w(
    const float* __restrict__ qw, const float* __restrict__ pw,
    unsigned short* __restrict__ wq, unsigned short* __restrict__ wp) {
  int row = blockIdx.x;
  const float* src; unsigned short* dst;
  if (row < 2304) { src = qw + (size_t)row * C_; dst = wq + (size_t)row * C_; }
  else { src = pw + (size_t)(row - 2304) * C_; dst = wp + (size_t)(row - 2304) * C_; }
  int c = threadIdx.x << 2;
  *(short4v*)(dst + c) = f4bf(*(const floatx4*)(src + c));
}

// ---------------------------------------------------------------------------
// 8-phase 256x256 bf16 GEMM core — UNCHANGED from verified R2.
// ---------------------------------------------------------------------------
#define LPA 0
#define LPB 16384
#define LQA 32768
#define LQB 49152

#define STAGE8(gp, ldsbase, ksk) {                                             \
    int kc_ = (ksk) < C_ ? (ksk) : 0;                                          \
    glds16((gp) + (size_t)arow * C_ + kc_ + (sgran << 3),                      \
           L + (ldsbase) + tid * 8);                                           \
    glds16((gp) + (size_t)(arow + 64) * C_ + kc_ + (sgran << 3),               \
           L + (ldsbase) + 4096 + tid * 8);                                    \
  }

#define PH8(q, AB, BB, LOADB, STG_STMT, WV) {                                  \
    if (LOADB) {                                                               \
      _Pragma("unroll") for (int n = 0; n < 4; n++)                            \
        _Pragma("unroll") for (int kk = 0; kk < 2; kk++)                       \
          bq[n][kk] = *(const short8*)&L[(BB) + rdB + n * 1024 +               \
                                          (((kk * 4 + quad) ^ swq) << 3)];     \
    }                                                                          \
    short8 a0k0 = *(const short8*)&L[(AB) + rdA + (2*(q))*1024 +               \
                                      (((quad) ^ swq) << 3)];                  \
    short8 a0k1 = *(const short8*)&L[(AB) + rdA + (2*(q))*1024 +               \
                                      (((4 + quad) ^ swq) << 3)];              \
    short8 a1k0 = *(const short8*)&L[(AB) + rdA + (2*(q)+1)*1024 +             \
                                      (((quad) ^ swq) << 3)];                  \
    short8 a1k1 = *(const short8*)&L[(AB) + rdA + (2*(q)+1)*1024 +             \
                                      (((4 + quad) ^ swq) << 3)];              \
    STG_STMT;                                                                  \
    asm volatile("s_barrier" ::: "memory");                                    \
    asm volatile("s_waitcnt lgkmcnt(0)" ::: "memory");                         \
    __builtin_amdgcn_sched_barrier(0);                                         \
    __builtin_amdgcn_s_setprio(1);                                             \
    _Pragma("unroll") for (int n = 0; n < 4; n++) {                            \
      acc[2*(q)][n]   = __builtin_amdgcn_mfma_f32_16x16x32_bf16(               \
          a0k0, bq[n][0], acc[2*(q)][n], 0, 0, 0);                             \
      acc[2*(q)+1][n] = __builtin_amdgcn_mfma_f32_16x16x32_bf16(               \
          a1k0, bq[n][0], acc[2*(q)+1][n], 0, 0, 0);                           \
      acc[2*(q)][n]   = __builtin_amdgcn_mfma_f32_16x16x32_bf16(               \
          a0k1, bq[n][1], acc[2*(q)][n], 0, 0, 0);                             \
      acc[2*(q)+1][n] = __builtin_amdgcn_mfma_f32_16x16x32_bf16(               \
          a1k1, bq[n][1], acc[2*(q)+1][n], 0, 0, 0);                           \
    }                                                                          \
    __builtin_amdgcn_s_setprio(0);                                             \
    if (WV) { asm volatile("s_waitcnt vmcnt(4)" ::: "memory"); }               \
    asm volatile("s_barrier" ::: "memory");                                    \
  }

#define GEMM8_CORE(Aptr, Bptr)                                                 \
  __shared__ short L[65536];                                                   \
  const int tid  = threadIdx.x;                                                \
  const int bm   = blockIdx.x;                                                 \
  const int bn   = blockIdx.y;                                                 \
  const int wave = tid >> 6, lane = tid & 63;                                  \
  const int wm   = wave >> 2, wn = wave & 3;                                   \
  const int l15  = lane & 15, quad = lane >> 4;                                \
  const int swq  = l15 & 7;                                                    \
  const int sgran = (tid & 7) ^ ((tid >> 3) & 7);                              \
  const int arow  = tid >> 3;                                                  \
  const unsigned short* gA = (Aptr) + (size_t)(bm * 256) * C_;                 \
  const unsigned short* gB = (Bptr) + (size_t)(bn * 256) * C_;                 \
  const unsigned short* gA1 = gA + (size_t)128 * C_;                           \
  const unsigned short* gB1 = gB + (size_t)128 * C_;                           \
  const int rdA = wm * 8192 + l15 * 64;                                        \
  const int rdB = (wn >> 1) * 8192 + ((wn & 1) * 64 + l15) * 64;               \
  floatx4 acc[8][4];                                                           \
  short8 bq[4][2];                                                             \
  _Pragma("unroll") for (int i = 0; i < 8; i++)                                \
      _Pragma("unroll") for (int j = 0; j < 4; j++)                            \
          acc[i][j] = {0.f, 0.f, 0.f, 0.f};                                    \
  /* prologue: P <- K-step 0 (A+B), Q.B <- K-step 1 */                         \
  STAGE8(gA,  LPA,        0); STAGE8(gA1, LPA + 8192, 0);                      \
  STAGE8(gB,  LPB,        0); STAGE8(gB1, LPB + 8192, 0);                      \
  STAGE8(gB,  LQB,       64); STAGE8(gB1, LQB + 8192, 64);                     \
  asm volatile("s_waitcnt vmcnt(4)" ::: "memory");                             \
  asm volatile("s_barrier" ::: "memory");                                      \
  for (int it = 0; it < 6; it++) {                                             \
    const int t  = it * 2;                                                     \
    const int kA1 = (t + 1) * 64;                                              \
    const int kN2 = (t + 2) * 64;                                              \
    const int kN3 = (t + 3) * 64;                                              \
    PH8(0, LPA, LPB, 1, STAGE8(gA,  LQA,        kA1), 0)                       \
    PH8(1, LPA, LPB, 0, STAGE8(gA1, LQA + 8192, kA1), 0)                       \
    PH8(2, LPA, LPB, 0, STAGE8(gB,  LPB,        kN2), 0)                       \
    PH8(3, LPA, LPB, 0, STAGE8(gB1, LPB + 8192, kN2), 1)                       \
    PH8(0, LQA, LQB, 1, STAGE8(gA,  LPA,        kN2), 0)                       \
    PH8(1, LQA, LQB, 0, STAGE8(gA1, LPA + 8192, kN2), 0)                       \
    PH8(2, LQA, LQB, 0, STAGE8(gB,  LQB,        kN3), 0)                       \
    PH8(3, LQA, LQB, 0, STAGE8(gB1, LQB + 8192, kN3), 1)                       \
  }

// QKV GEMM (UNCHANGED, verified): grid (128, 9).
__global__ __launch_bounds__(512, 2) void qkv_gemm_bf8(
    const unsigned short* __restrict__ a,
    const unsigned short* __restrict__ w,
    unsigned short* __restrict__ qkv) {
  GEMM8_CORE(a, w)
  const int which = bn / 3;
  const int jbase = (bn - which * 3) * 256;
  unsigned short* dst = qkv + (size_t)which * QKV_PLANE;
#pragma unroll
  for (int mi = 0; mi < 8; mi++) {
#pragma unroll
    for (int r = 0; r < 4; r++) {
      int mg = bm * 256 + wm * 128 + mi * 16 + quad * 4 + r;
      int b = mg >> 12, p = mg & 4095;
      int wdx = p >> 8, tt = p & 255;
      size_t base = (size_t)((b * 16 + wdx) * 12) * (NW_ * HD_) + (size_t)tt * HD_;
#pragma unroll
      for (int ni = 0; ni < 4; ni++) {
        int jj = jbase + wn * 64 + ni * 16 + l15;
        int h = jj >> 6, d = jj & 63;
        dst[base + (size_t)h * (NW_ * HD_) + d] = f2bf(acc[mi][ni][r]);
      }
    }
  }
  asm volatile("s_waitcnt vmcnt(0)" ::: "memory");
}

// ---------------------------------------------------------------------------
// Proj GEMM R3: 128x256 tile, 8-phase, BK=64, grid (256,3) = 768 blocks.
// LDS 96 KB: PA[128x64]=8192s, PB[256x64]=16384s, QA=8192s, QB=16384s.
// Same staging/vmcnt skeleton as qkv (hazard analysis identical):
//   ph1: Q.A(t+1), ph2/3: P.B(t+2), ph4: vmcnt(4) [Q.A done, P.B in flight]
//   ph5: P.A(t+2), ph6/7: Q.B(t+3), ph8: vmcnt(4) [P.B+P.A done, Q.B fly]
// ---------------------------------------------------------------------------
#define JPA 0
#define JPB 8192
#define JQA 24576
#define JQB 32768

#define PH4P(q, AB, BB, LOADB, STG_STMT, WV) {                                 \
    if (LOADB) {                                                               \
      _Pragma("unroll") for (int n = 0; n < 4; n++)                            \
        _Pragma("unroll") for (int kk = 0; kk < 2; kk++)                       \
          bq[n][kk] = *(const short8*)&L[(BB) + rdB + n * 1024 +               \
                                          (((kk * 4 + quad) ^ swq) << 3)];     \
    }                                                                          \
    short8 a0k0 = *(const short8*)&L[(AB) + rdA + (q)*1024 +                   \
                                      (((quad) ^ swq) << 3)];                  \
    short8 a0k1 = *(const short8*)&L[(AB) + rdA + (q)*1024 +                   \
                                      (((4 + quad) ^ swq) << 3)];              \
    STG_STMT;                                                                  \
    asm volatile("s_barrier" ::: "memory");                                    \
    asm volatile("s_waitcnt lgkmcnt(0)" ::: "memory");                         \
    __builtin_amdgcn_sched_barrier(0);                                         \
    __builtin_amdgcn_s_setprio(1);                                             \
    _Pragma("unroll") for (int n = 0; n < 4; n++) {                            \
      acc[q][n] = __builtin_amdgcn_mfma_f32_16x16x32_bf16(                     \
          a0k0, bq[n][0], acc[q][n], 0, 0, 0);                                 \
      acc[q][n] = __builtin_amdgcn_mfma_f32_16x16x32_bf16(                     \
          a0k1, bq[n][1], acc[q][n], 0, 0, 0);                                 \
    }                                                                          \
    __builtin_amdgcn_s_setprio(0);                                             \
    if (WV) { asm volatile("s_waitcnt vmcnt(4)" ::: "memory"); }               \
    asm volatile("s_barrier" ::: "memory");                                    \
  }

__global__ __launch_bounds__(512, 2) void proj_gemm_bf8(
    const unsigned short* __restrict__ a,
    const unsigned short* __restrict__ w,
    const float* __restrict__ bias,
    float* __restrict__ out) {
  __shared__ short L[49152];
  const int tid  = threadIdx.x;
  const int bm   = blockIdx.x;                 // 0..255 (M tiles of 128)
  const int bn   = blockIdx.y;                 // 0..2   (N tiles of 256)
  const int wave = tid >> 6, lane = tid & 63;
  const int wm   = wave >> 2, wn = wave & 3;   // 2M x 4N waves, 64x64 each
  const int l15  = lane & 15, quad = lane >> 4;
  const int swq  = l15 & 7;
  const int sgran = (tid & 7) ^ ((tid >> 3) & 7);
  const int arow  = tid >> 3;
  const unsigned short* gA  = a + (size_t)(bm * 128) * C_;
  const unsigned short* gB  = w + (size_t)(bn * 256) * C_;
  const unsigned short* gB1 = gB + (size_t)128 * C_;
  const int rdA = wm * 4096 + l15 * 64;
  const int rdB = wn * 4096 + l15 * 64;
  floatx4 acc[4][4];
  short8 bq[4][2];
#pragma unroll
  for (int i = 0; i < 4; i++)
#pragma unroll
    for (int j = 0; j < 4; j++) acc[i][j] = {0.f, 0.f, 0.f, 0.f};
  // prologue: P.A(0), P.B(0), Q.B(1)
  STAGE8(gA,  JPA,        0);
  STAGE8(gB,  JPB,        0); STAGE8(gB1, JPB + 8192, 0);
  STAGE8(gB,  JQB,       64); STAGE8(gB1, JQB + 8192, 64);
  asm volatile("s_waitcnt vmcnt(4)" ::: "memory");
  asm volatile("s_barrier" ::: "memory");
  for (int it = 0; it < 6; it++) {
    const int t  = it * 2;
    const int kA1 = (t + 1) * 64;
    const int kN2 = (t + 2) * 64;
    const int kN3 = (t + 3) * 64;
    PH4P(0, JPA, JPB, 1, STAGE8(gA,  JQA,        kA1), 0)
    PH4P(1, JPA, JPB, 0, STAGE8(gB,  JPB,        kN2), 0)
    PH4P(2, JPA, JPB, 0, STAGE8(gB1, JPB + 8192, kN2), 0)
    PH4P(3, JPA, JPB, 0, {;}, 1)
    PH4P(0, JQA, JQB, 1, STAGE8(gA,  JPA,        kN2), 0)
    PH4P(1, JQA, JQB, 0, STAGE8(gB,  JQB,        kN3), 0)
    PH4P(2, JQA, JQB, 0, STAGE8(gB1, JQB + 8192, kN3), 0)
    PH4P(3, JQA, JQB, 0, {;}, 1)
  }
#pragma unroll
  for (int mi = 0; mi < 4; mi++) {
#pragma unroll
    for (int r = 0; r < 4; r++) {
      int mg = bm * 128 + wm * 64 + mi * 16 + quad * 4 + r;
      size_t rowb = (size_t)mg * C_;
#pragma unroll
      for (int ni = 0; ni < 4; ni++) {
        int jj = bn * 256 + wn * 64 + ni * 16 + l15;
        out[rowb + jj] = acc[mi][ni][r] + bias[jj];
      }
    }
  }
  asm volatile("s_waitcnt vmcnt(0)" ::: "memory");
}

// ---------------------------------------------------------------------------
// MFMA flash attention R3: double-buffered K/V LDS, loads for tile t+1 issued
// before compute of tile t (T14); one barrier per iteration; setprio (T5).
// LDS: Ks[2]+Vt[2] (4x9.2KB) + Ps (18.4KB) = 55 KB -> 2 blocks/CU.
// ---------------------------------------------------------------------------
__global__ __launch_bounds__(512, 2) void attn_mfma(
    const unsigned short* __restrict__ qkv,
    unsigned short* __restrict__ attn_out) {
  const int bwh = blockIdx.x;
  const int tid = threadIdx.x;
  const int wv = tid >> 6, lane = tid & 63;
  const int l15 = lane & 15, quad = lane >> 4;
  const size_t off = (size_t)bwh * (NW_ * HD_);
  const unsigned short* qb = qkv + off;
  const unsigned short* kb = qkv + QKV_PLANE + off;
  const unsigned short* vb = qkv + 2 * QKV_PLANE + off;

  __shared__ short Ks[2][64 * 72];
  __shared__ short Vt[2][64 * 72];
  __shared__ short Ps[8][16 * 72];

  const int sr = tid >> 3;
  const int sc = (tid & 7) << 3;

  // issue K/V tile-0 loads and Q loads together (latency overlaps)
  short8 kk = *(const short8*)(kb + sr * 64 + sc);
  short8 vv = *(const short8*)(vb + sr * 64 + sc);

  short8 bq[2][2];
#pragma unroll
  for (int c = 0; c < 2; c++) {
    int mc = wv + 8 * c;
#pragma unroll
    for (int kc = 0; kc < 2; kc++)
      bq[c][kc] = *(const short8*)(qb + (mc * 16 + l15) * 64 + kc * 32 + quad * 8);
  }

  floatx4 O[2][4];
#pragma unroll
  for (int c = 0; c < 2; c++)
#pragma unroll
    for (int dt = 0; dt < 4; dt++) O[c][dt] = {0.f, 0.f, 0.f, 0.f};
  float m_run[2] = {-1e30f, -1e30f};
  float l_run[2] = {0.f, 0.f};

  for (int t = 0; t < 4; t++) {
    const int buf = t & 1;
    // write staged regs -> LDS (waits vmcnt internally via compiler)
    *(short8*)&Ks[buf][sr * 72 + sc] = kk;
#pragma unroll
    for (int j = 0; j < 8; j++) Vt[buf][(sc + j) * 72 + sr] = vv[j];
    // issue next tile's loads early; latency hides under compute of t
    if (t < 3) {
      kk = *(const short8*)(kb + ((t + 1) * 64 + sr) * 64 + sc);
      vv = *(const short8*)(vb + ((t + 1) * 64 + sr) * 64 + sc);
    }
    __syncthreads();   // writes of buf visible; reads of buf from t-2 done
                       // (separated by barrier at t-1)

#pragma unroll
    for (int c = 0; c < 2; c++) {
      floatx4 st[4];
      __builtin_amdgcn_s_setprio(1);
#pragma unroll
      for (int nt = 0; nt < 4; nt++) {
        short8 ak0 = *(const short8*)&Ks[buf][(nt * 16 + l15) * 72 + quad * 8];
        short8 ak1 = *(const short8*)&Ks[buf][(nt * 16 + l15) * 72 + 32 + quad * 8];
        floatx4 z = {0.f, 0.f, 0.f, 0.f};
        z = __builtin_amdgcn_mfma_f32_16x16x32_bf16(ak0, bq[c][0], z, 0, 0, 0);
        z = __builtin_amdgcn_mfma_f32_16x16x32_bf16(ak1, bq[c][1], z, 0, 0, 0);
        st[nt] = z;
      }
      __builtin_amdgcn_s_setprio(0);
      float s[16];
      float cmax = -1e30f;
#pragma unroll
      for (int nt = 0; nt < 4; nt++)
#pragma unroll
        for (int r = 0; r < 4; r++) {
          float v = st[nt][r] * SCALE_;
          s[nt * 4 + r] = v;
          cmax = fmaxf(cmax, v);
        }
      cmax = fmaxf(cmax, __shfl_xor(cmax, 16));
      cmax = fmaxf(cmax, __shfl_xor(cmax, 32));
      float nm = fmaxf(m_run[c], cmax);
      float alpha = __expf(m_run[c] - nm);
      m_run[c] = nm;
      float psum = 0.f;
#pragma unroll
      for (int j = 0; j < 16; j++) {
        float p = __expf(s[j] - nm);
        s[j] = p;
        psum += p;
      }
      psum += __shfl_xor(psum, 16);
      psum += __shfl_xor(psum, 32);
      l_run[c] = l_run[c] * alpha + psum;
#pragma unroll
      for (int nt = 0; nt < 4; nt++) {
        short4v pv;
        pv[0] = (short)f2bf(s[nt * 4 + 0]);
        pv[1] = (short)f2bf(s[nt * 4 + 1]);
        pv[2] = (short)f2bf(s[nt * 4 + 2]);
        pv[3] = (short)f2bf(s[nt * 4 + 3]);
        *(short4v*)&Ps[wv][l15 * 72 + nt * 16 + quad * 4] = pv;
      }
      float ar[4];
#pragma unroll
      for (int r = 0; r < 4; r++) ar[r] = __shfl(alpha, quad * 4 + r);
#pragma unroll
      for (int dt = 0; dt < 4; dt++)
#pragma unroll
        for (int r = 0; r < 4; r++) O[c][dt][r] *= ar[r];
      __builtin_amdgcn_s_setprio(1);
#pragma unroll
      for (int kc = 0; kc < 2; kc++) {
        short8 ap = *(const short8*)&Ps[wv][l15 * 72 + kc * 32 + quad * 8];
#pragma unroll
        for (int dt = 0; dt < 4; dt++) {
          short8 bv = *(const short8*)&Vt[buf][(dt * 16 + l15) * 72 + kc * 32 + quad * 8];
          O[c][dt] = __builtin_amdgcn_mfma_f32_16x16x32_bf16(ap, bv, O[c][dt], 0, 0, 0);
        }
      }
      __builtin_amdgcn_s_setprio(0);
    }
  }

  int h = bwh % 12, bw = bwh / 12;
  int b = bw >> 4, wdx = bw & 15;
#pragma unroll
  for (int c = 0; c < 2; c++) {
    float linv = 1.f / l_run[c];
    float lr[4];
#pragma unroll
    for (int r = 0; r < 4; r++) lr[r] = __shfl(linv, quad * 4 + r);
    int mc = wv + 8 * c;
#pragma unroll
    for (int r = 0; r < 4; r++) {
      int q = mc * 16 + quad * 4 + r;
      int n = perm_n(wdx, q);
      unsigned short* op = attn_out + ((size_t)(b * N_ + n)) * C_ + h * HD_;
#pragma unroll
      for (int dt = 0; dt < 4; dt++)
        op[dt * 16 + l15] = f2bf(O[c][dt][r] * lr[r]);
    }
  }
}

// ---------------------------------------------------------------------------
// FALLBACK kernels (used only if ws_size < 206 MB)
// ---------------------------------------------------------------------------
__global__ __launch_bounds__(256) void qkv_gemm_f32(
    const float* __restrict__ x,
    const float* __restrict__ w,
    unsigned short* __restrict__ qkv) {
  __shared__ short As[128 * 40];
  __shared__ short Bs[128 * 40];
  const int tid  = threadIdx.x;
  const int bm   = blockIdx.x;
  const int bn   = blockIdx.y;
  const int wave = tid >> 6, lane = tid & 63;
  const int wm   = wave >> 1, wn = wave & 1;
  const int l15  = lane & 15, quad = lane >> 4;
  const int colf  = (tid & 7) << 2;
  const int rbase = tid >> 3;
  size_t aoff[4], boff[4];
#pragma unroll
  for (int i = 0; i < 4; i++) {
    int r = rbase + 32 * i;
    int mg = bm * 128 + r;
    int b = mg >> 12, p = mg & 4095;
    int n = perm_n(p >> 8, p & 255);
    aoff[i] = ((size_t)(b << 12) + (size_t)n) * C_;
    boff[i] = (size_t)(bn * 128 + r) * C_;
  }
  floatx4 acc[4][4];
#pragma unroll
  for (int i = 0; i < 4; i++)
#pragma unroll
    for (int j = 0; j < 4; j++) acc[i][j] = {0.f, 0.f, 0.f, 0.f};
  for (int k0 = 0; k0 < C_; k0 += 32) {
#pragma unroll
    for (int i = 0; i < 4; i++) {
      int r = rbase + 32 * i;
      *(short4v*)&As[r * 40 + colf] = f4bf(*(const floatx4*)(x + aoff[i] + k0 + colf));
      *(short4v*)&Bs[r * 40 + colf] = f4bf(*(const floatx4*)(w + boff[i] + k0 + colf));
    }
    __syncthreads();
    short8 af[4], bfr[4];
#pragma unroll
    for (int mi = 0; mi < 4; mi++)
      af[mi] = *(const short8*)&As[(wm * 64 + mi * 16 + l15) * 40 + quad * 8];
#pragma unroll
    for (int ni = 0; ni < 4; ni++)
      bfr[ni] = *(const short8*)&Bs[(wn * 64 + ni * 16 + l15) * 40 + quad * 8];
#pragma unroll
    for (int mi = 0; mi < 4; mi++)
#pragma unroll
      for (int ni = 0; ni < 4; ni++)
        acc[mi][ni] = __builtin_amdgcn_mfma_f32_16x16x32_bf16(
            af[mi], bfr[ni], acc[mi][ni], 0, 0, 0);
    __syncthreads();
  }
  const int which = (bn * 128) / 768;
  const int jbase = bn * 128 - which * 768;
  unsigned short* dst = qkv + (size_t)which * QKV_PLANE;
#pragma unroll
  for (int mi = 0; mi < 4; mi++) {
#pragma unroll
    for (int r = 0; r < 4; r++) {
      int mg = bm * 128 + wm * 64 + mi * 16 + quad * 4 + r;
      int b = mg >> 12, p = mg & 4095;
      int wdx = p >> 8, t = p & 255;
      size_t base = (size_t)((b * 16 + wdx) * 12) * (NW_ * HD_) + (size_t)t * HD_;
#pragma unroll
      for (int ni = 0; ni < 4; ni++) {
        int jj = jbase + wn * 64 + ni * 16 + l15;
        int h = jj >> 6, d = jj & 63;
        dst[base + (size_t)h * (NW_ * HD_) + d] = f2bf(acc[mi][ni][r]);
      }
    }
  }
}

__global__ __launch_bounds__(256) void proj_gemm_f32(
    const unsigned short* __restrict__ a,
    const float* __restrict__ w,
    const float* __restrict__ bias,
    float* __restrict__ out) {
  __shared__ short As[128 * 40];
  __shared__ short Bs[128 * 40];
  const int tid  = threadIdx.x;
  const int bm   = blockIdx.x;
  const int bn   = blockIdx.y;
  const int wave = tid >> 6, lane = tid & 63;
  const int wm   = wave >> 1, wn = wave & 1;
  const int l15  = lane & 15, quad = lane >> 4;
  const int c0 = tid, c1 = tid + 256;
  const int r0 = c0 >> 2, kc0 = (c0 & 3) << 3;
  const int r1 = c1 >> 2, kc1 = (c1 & 3) << 3;
  const size_t a0 = (size_t)(bm * 128 + r0) * C_;
  const size_t a1 = (size_t)(bm * 128 + r1) * C_;
  const int colf  = (tid & 7) << 2;
  const int rbase = tid >> 3;
  size_t boff[4];
#pragma unroll
  for (int i = 0; i < 4; i++)
    boff[i] = (size_t)(bn * 128 + rbase + 32 * i) * C_;
  floatx4 acc[4][4];
#pragma unroll
  for (int i = 0; i < 4; i++)
#pragma unroll
    for (int j = 0; j < 4; j++) acc[i][j] = {0.f, 0.f, 0.f, 0.f};
  for (int k0 = 0; k0 < C_; k0 += 32) {
    *(short8*)&As[r0 * 40 + kc0] = *(const short8*)(a + a0 + k0 + kc0);
    *(short8*)&As[r1 * 40 + kc1] = *(const short8*)(a + a1 + k0 + kc1);
#pragma unroll
    for (int i = 0; i < 4; i++) {
      int r = rbase + 32 * i;
      *(short4v*)&Bs[r * 40 + colf] = f4bf(*(const floatx4*)(w + boff[i] + k0 + colf));
    }
    __syncthreads();
    short8 af[4], bfr[4];
#pragma unroll
    for (int mi = 0; mi < 4; mi++)
      af[mi] = *(const short8*)&As[(wm * 64 + mi * 16 + l15) * 40 + quad * 8];
#pragma unroll
    for (int ni = 0; ni < 4; ni++)
      bfr[ni] = *(const short8*)&Bs[(wn * 64 + ni * 16 + l15) * 40 + quad * 8];
#pragma unroll
    for (int mi = 0; mi < 4; mi++)
#pragma unroll
      for (int ni = 0; ni < 4; ni++)
        acc[mi][ni] = __builtin_amdgcn_mfma_f32_16x16x32_bf16(
            af[mi], bfr[ni], acc[mi][ni], 0, 0, 0);
    __syncthreads();
  }
#pragma unroll
  for (int mi = 0; mi < 4; mi++) {
#pragma unroll
    for (int r = 0; r < 4; r++) {
      int mg = bm * 128 + wm * 64 + mi * 16 + quad * 4 + r;
      size_t rowb = (size_t)mg * C_;
#pragma unroll
      for (int ni = 0; ni < 4; ni++) {
        int jj = bn * 128 + wn * 64 + ni * 16 + l15;
        out[rowb + jj] = acc[mi][ni][r] + bias[jj];
      }
    }
  }
}

extern "C" void kernel_launch(void* const* d_in, const int* in_sizes, int n_in,
                              void* d_out, int out_size, void* d_ws, size_t ws_size,
                              hipStream_t stream) {
  const float* x  = (const float*)d_in[0];
  const float* qw = (const float*)d_in[1];
  const float* pw = (const float*)d_in[2];
  const float* pb = (const float*)d_in[3];
  float* out = (float*)d_out;
  unsigned short* ws = (unsigned short*)d_ws;

  unsigned short* xb       = ws;                    // plane 0 (xb, then attn_buf)
  unsigned short* qkv_buf  = ws + QKV_PLANE;        // planes 1..3 = q,k,v
  unsigned short* attn_buf = ws;                    // reuses plane 0
  unsigned short* wb_qkv   = ws + 4 * QKV_PLANE;                  // 2304*768
  unsigned short* wb_proj  = wb_qkv + (size_t)2304 * 768;         // 768*768

  const size_t need = (4 * QKV_PLANE + (size_t)2304 * 768 + (size_t)768 * 768) * 2;
  if (ws_size >= need) {
    conv_x<<<dim3(B_ * N_), dim3(192), 0, stream>>>(x, xb);
    conv_w<<<dim3(3072), dim3(192), 0, stream>>>(qw, pw, wb_qkv, wb_proj);
    qkv_gemm_bf8<<<dim3(128, 9), dim3(512), 0, stream>>>(xb, wb_qkv, qkv_buf);
    attn_mfma<<<dim3(1536), dim3(512), 0, stream>>>(qkv_buf, attn_buf);
    proj_gemm_bf8<<<dim3(256, 3), dim3(512), 0, stream>>>(attn_buf, wb_proj, pb, out);
  } else {
    qkv_gemm_f32<<<dim3(256, 18), dim3(256), 0, stream>>>(x, qw, qkv_buf);
    attn_mfma<<<dim3(1536), dim3(512), 0, stream>>>(qkv_buf, attn_buf);
    proj_gemm_f32<<<dim3(256, 6), dim3(256), 0, stream>>>(attn_buf, pw, pb, out);
  }
}